// Round 1
// 211.764 us; speedup vs baseline: 1.0485x; 1.0485x over previous
//
#include <hip/hip_runtime.h>

// Reference collapses: softmax over a size-1 key axis == 1.0, so
// out[bn,t,:] = padded[bn,t,:] + (masked_mean_t(padded[bn]) @ Wv + bv).
// q/k/rope/positions/sum_token are dead code.
//
// R5: single fully-fused kernel. The reduction is per-bn over T=128 rows
// only -> one block owns one bn end-to-end, NO cross-block dependency and
// NO grid sync (unlike the R3 fusion, which serialized phases chip-wide).
// Each thread keeps its 16 float4 of padded resident in registers, so
// padded is read from HBM exactly once:
//   phase 1: load 128x384 tile into regs, masked column-sums via LDS tree
//   phase 2: summary = colsum * 1/denom  (96 threads)
//   phase 3: matvec v = summary @ Wv + bv (Wv stays L2-resident: 576 KB,
//            read once per block, 512 blocks -> ~295 MB L2 traffic, ~0 HBM)
//   phase 4: out = regs + v  (write once)
// HBM traffic: 100.7 MB read + 100.7 MB write + masks (vs 302 MB for the
// 3-kernel split) and 1 dispatch instead of 3.

#define DM 384
#define TT 128
#define C4 96          // DM / 4
#define BN_TOT 512
#define NR  8          // row-groups (768 threads = 8 * 96)
#define RPT 16         // rows per thread = 128 / 8

__global__ __launch_bounds__(768) void fused_mean_matvec_add(
    const float* __restrict__ padded,
    const int*   __restrict__ masks,
    const float* __restrict__ Wv,
    const float* __restrict__ bv,
    float*       __restrict__ out)
{
    const int bn = blockIdx.x;
    const int t  = threadIdx.x;
    const int c  = t % C4;        // float4 column 0..95
    const int r  = t / C4;        // row-group 0..7

    __shared__ float  w_sh[TT];
    __shared__ float4 part_sh[NR][C4];   // 12 KB
    __shared__ float  summ[DM];
    __shared__ float4 v_sh[C4];

    const float4* __restrict__ p4 =
        (const float4*)padded + (size_t)bn * TT * C4;

    // ---- phase 1a: issue all 16 resident loads (independent of masks) ----
    float4 x[RPT];
    #pragma unroll
    for (int i = 0; i < RPT; ++i) {
        x[i] = p4[(r + i * NR) * C4 + c];
    }

    if (t < TT) w_sh[t] = (float)masks[bn * TT + t];
    __syncthreads();

    // ---- phase 1b: masked column partial sums (16 rows per thread) ----
    float4 acc = make_float4(0.f, 0.f, 0.f, 0.f);
    #pragma unroll
    for (int i = 0; i < RPT; ++i) {
        const float w = w_sh[r + i * NR];
        acc.x += x[i].x * w; acc.y += x[i].y * w;
        acc.z += x[i].z * w; acc.w += x[i].w * w;
    }
    part_sh[r][c] = acc;
    __syncthreads();

    // ---- phase 2: finalize summary (96 threads) ----
    if (t < C4) {
        float dsum = 0.f;
        #pragma unroll
        for (int i = 0; i < TT; ++i) dsum += w_sh[i];   // LDS broadcast reads
        const float inv = 1.0f / fmaxf(dsum, 1e-6f);

        float4 s = part_sh[0][t];
        #pragma unroll
        for (int g = 1; g < NR; ++g) {
            const float4 p = part_sh[g][t];
            s.x += p.x; s.y += p.y; s.z += p.z; s.w += p.w;
        }
        s.x *= inv; s.y *= inv; s.z *= inv; s.w *= inv;
        ((float4*)summ)[t] = s;
    }
    __syncthreads();

    // ---- phase 3: matvec v = summary @ Wv + bv ----
    // row-group r covers Wv rows [r*48, r*48+48); block reads Wv exactly once.
    float4 a = make_float4(0.f, 0.f, 0.f, 0.f);
    const float4* __restrict__ wv4 = (const float4*)Wv;
    const int e0 = r * (DM / NR);
    #pragma unroll 8
    for (int i = 0; i < DM / NR; ++i) {
        const int   e = e0 + i;
        const float s = summ[e];                       // LDS broadcast
        const float4 w = wv4[(size_t)e * C4 + c];      // coalesced, L2-hot
        a.x += s * w.x; a.y += s * w.y; a.z += s * w.z; a.w += s * w.w;
    }
    part_sh[r][c] = a;
    __syncthreads();

    if (t < C4) {
        float4 v = ((const float4*)bv)[t];
        #pragma unroll
        for (int g = 0; g < NR; ++g) {
            const float4 p = part_sh[g][t];
            v.x += p.x; v.y += p.y; v.z += p.z; v.w += p.w;
        }
        v_sh[t] = v;
    }
    __syncthreads();

    // ---- phase 4: out = resident padded + v ----
    const float4 v = v_sh[c];
    float4* __restrict__ o4 = (float4*)out + (size_t)bn * TT * C4;
    #pragma unroll
    for (int i = 0; i < RPT; ++i) {
        float4 y = x[i];
        y.x += v.x; y.y += v.y; y.z += v.z; y.w += v.w;
        o4[(r + i * NR) * C4 + c] = y;
    }
}

extern "C" void kernel_launch(void* const* d_in, const int* in_sizes, int n_in,
                              void* d_out, int out_size, void* d_ws, size_t ws_size,
                              hipStream_t stream) {
    const float* padded = (const float*)d_in[0];
    // d_in[1] sum_token, d_in[2] positions_3d, d_in[3..6] Wq/bq/Wk/bk: dead
    const float* Wv     = (const float*)d_in[7];
    const float* bv     = (const float*)d_in[8];
    const int*   masks  = (const int*)d_in[9];
    float* out = (float*)d_out;

    fused_mean_matvec_add<<<BN_TOT, 768, 0, stream>>>(padded, masks, Wv, bv, out);
}